// Round 3
// baseline (95.279 us; speedup 1.0000x reference)
//
#include <hip/hip_runtime.h>

// Problem shape (fixed by setup_inputs): B=8, P=256 bins, M=240*320=76800 pixels.
#define NB     8
#define NP     256
#define MPB    76800
#define SLICES 128
#define PER    (MPB / SLICES)   // 600 targets per slice, divisible by 4

#define MIN_DEPTH 0.001f

// Stage 1: block = (slice s, batch b), 128 threads; thread owns bin centers
// tid and tid+128. Targets read directly from global with wave-uniform
// addresses (broadcast / scalarizable; slice is L1-resident at 2.4 KB).
// Plain coalesced stores of per-slice minima — no atomics.
__global__ __launch_bounds__(128) void chamfer_stage1(
    const float* __restrict__ bins,
    const float* __restrict__ targets,
    float* __restrict__ partial) {
    const int b   = blockIdx.y;
    const int s   = blockIdx.x;
    const int tid = threadIdx.x;

    const float c0 = 0.5f * (bins[b * (NP + 1) + tid]       + bins[b * (NP + 1) + tid + 1]);
    const float c1 = 0.5f * (bins[b * (NP + 1) + tid + 128] + bins[b * (NP + 1) + tid + 129]);

    const float4* src = reinterpret_cast<const float4*>(
        targets + (size_t)b * MPB + (size_t)s * PER);

    float a00 = 1e30f, a01 = 1e30f, a10 = 1e30f, a11 = 1e30f;
#pragma unroll 5
    for (int i = 0; i < PER / 4; ++i) {
        float4 t = src[i];
        t.x = (t.x >= MIN_DEPTH) ? t.x : 0.0f;
        t.y = (t.y >= MIN_DEPTH) ? t.y : 0.0f;
        t.z = (t.z >= MIN_DEPTH) ? t.z : 0.0f;
        t.w = (t.w >= MIN_DEPTH) ? t.w : 0.0f;
        a00 = fminf(a00, fminf(fabsf(c0 - t.x), fabsf(c0 - t.y)));
        a01 = fminf(a01, fminf(fabsf(c0 - t.z), fabsf(c0 - t.w)));
        a10 = fminf(a10, fminf(fabsf(c1 - t.x), fabsf(c1 - t.y)));
        a11 = fminf(a11, fminf(fabsf(c1 - t.z), fabsf(c1 - t.w)));
    }

    float* dst = partial + ((size_t)b * SLICES + s) * NP;
    dst[tid]       = fminf(a00, a01);   // coalesced: tid = 0..127
    dst[tid + 128] = fminf(a10, a11);   // coalesced: 128..255
}

// Stage 2: one block per batch; thread p min-reduces over the 128 slice
// partials (coalesced: consecutive p -> consecutive addresses), then the
// block sums its 256 minima and writes one partial sum per batch.
__global__ __launch_bounds__(256) void chamfer_stage2(
    const float* __restrict__ partial,
    float* __restrict__ sums) {
    const int b = blockIdx.x;
    const int p = threadIdx.x;

    const float* base = partial + (size_t)b * SLICES * NP + p;
    float m = 1e30f;
#pragma unroll 8
    for (int s = 0; s < SLICES; ++s)
        m = fminf(m, base[(size_t)s * NP]);

    // block sum: wave64 shuffle reduce, then across the 4 waves via LDS
    float v = m;
    for (int off = 32; off > 0; off >>= 1)
        v += __shfl_down(v, off, 64);
    __shared__ float w[4];
    if ((p & 63) == 0) w[p >> 6] = v;
    __syncthreads();
    if (p == 0) sums[b] = w[0] + w[1] + w[2] + w[3];
}

// Stage 3: fold the 8 per-batch sums into the output scalar.
__global__ __launch_bounds__(64) void chamfer_stage3(
    const float* __restrict__ sums,
    float* __restrict__ out) {
    if (threadIdx.x == 0) {
        float s = 0.0f;
        for (int b = 0; b < NB; ++b) s += sums[b];
        out[0] = s;
    }
}

extern "C" void kernel_launch(void* const* d_in, const int* in_sizes, int n_in,
                              void* d_out, int out_size, void* d_ws, size_t ws_size,
                              hipStream_t stream) {
    const float* bins    = (const float*)d_in[0];
    const float* targets = (const float*)d_in[1];
    float* out           = (float*)d_out;

    float* partial = (float*)d_ws;                       // [NB][SLICES][NP]
    float* sums    = partial + (size_t)NB * SLICES * NP; // [NB]

    dim3 grid1(SLICES, NB);
    chamfer_stage1<<<grid1, 128, 0, stream>>>(bins, targets, partial);
    chamfer_stage2<<<NB, 256, 0, stream>>>(partial, sums);
    chamfer_stage3<<<1, 64, 0, stream>>>(sums, out);
}

// Round 6
// 70.137 us; speedup vs baseline: 1.3585x; 1.3585x over previous
//
#include <hip/hip_runtime.h>

// Problem shape (fixed by setup_inputs): B=8, P=256 bins, M=240*320=76800 pixels.
#define NB   8
#define NP   256
#define MPB  76800
#define WPB  4                    // waves (= target slices) per block
#define PER  600                  // targets per wave; divisible by 4
#define GPB  (MPB / (WPB * PER))  // 32 blocks per batch
#define MIN_DEPTH 0.001f

// Stage 1: block = (group g, batch b), 256 threads = 4 waves.
// Block stages 2400 targets in LDS (mask applied once at staging).
// Each wave scans its own 600-target slice; each LANE owns 4 bins
// (l, l+64, l+128, l+192), so one broadcast ds_read_b128 feeds 16 pair-ops
// (4x fewer LDS broadcasts than 1-bin/thread). Cross-wave min via LDS,
// plain coalesced store of 256 per-block minima. No atomics.
__global__ __launch_bounds__(256) void chamfer_stage1(
    const float* __restrict__ bins,
    const float* __restrict__ targets,
    float* __restrict__ partial) {
    const int b   = blockIdx.y;
    const int g   = blockIdx.x;
    const int tid = threadIdx.x;
    const int w   = tid >> 6;     // wave 0..3
    const int l   = tid & 63;     // lane

    __shared__ float sh[WPB * PER];    // 9.6 KB staged targets
    __shared__ float red[WPB][NP];     // 4 KB cross-wave reduce

    const float4* src = reinterpret_cast<const float4*>(
        targets + (size_t)b * MPB + (size_t)g * (WPB * PER));
    float4* dst = reinterpret_cast<float4*>(sh);
    for (int i = tid; i < WPB * PER / 4; i += 256) {
        float4 t = src[i];
        t.x = (t.x >= MIN_DEPTH) ? t.x : 0.0f;
        t.y = (t.y >= MIN_DEPTH) ? t.y : 0.0f;
        t.z = (t.z >= MIN_DEPTH) ? t.z : 0.0f;
        t.w = (t.w >= MIN_DEPTH) ? t.w : 0.0f;
        dst[i] = t;
    }

    const float* bb = bins + b * (NP + 1);
    const float c0 = 0.5f * (bb[l]       + bb[l + 1]);
    const float c1 = 0.5f * (bb[l + 64]  + bb[l + 65]);
    const float c2 = 0.5f * (bb[l + 128] + bb[l + 129]);
    const float c3 = 0.5f * (bb[l + 192] + bb[l + 193]);

    __syncthreads();

    // 8 independent accumulator chains (2 per bin) for ILP.
    float m00 = 1e30f, m01 = 1e30f, m10 = 1e30f, m11 = 1e30f;
    float m20 = 1e30f, m21 = 1e30f, m30 = 1e30f, m31 = 1e30f;
    const float4* t4 = reinterpret_cast<const float4*>(sh + w * PER);
#pragma unroll 5
    for (int i = 0; i < PER / 4; ++i) {
        float4 t = t4[i];   // broadcast read: all lanes same address
        // fminf(acc, fminf(|a|,|b|)) -> v_min3_f32 with abs modifiers
        m00 = fminf(m00, fminf(fabsf(c0 - t.x), fabsf(c0 - t.y)));
        m01 = fminf(m01, fminf(fabsf(c0 - t.z), fabsf(c0 - t.w)));
        m10 = fminf(m10, fminf(fabsf(c1 - t.x), fabsf(c1 - t.y)));
        m11 = fminf(m11, fminf(fabsf(c1 - t.z), fabsf(c1 - t.w)));
        m20 = fminf(m20, fminf(fabsf(c2 - t.x), fabsf(c2 - t.y)));
        m21 = fminf(m21, fminf(fabsf(c2 - t.z), fabsf(c2 - t.w)));
        m30 = fminf(m30, fminf(fabsf(c3 - t.x), fabsf(c3 - t.y)));
        m31 = fminf(m31, fminf(fabsf(c3 - t.z), fabsf(c3 - t.w)));
    }

    red[w][l]       = fminf(m00, m01);
    red[w][l + 64]  = fminf(m10, m11);
    red[w][l + 128] = fminf(m20, m21);
    red[w][l + 192] = fminf(m30, m31);
    __syncthreads();

    const float m = fminf(fminf(red[0][tid], red[1][tid]),
                          fminf(red[2][tid], red[3][tid]));
    partial[((size_t)b * GPB + g) * NP + tid] = m;   // coalesced
}

// Stage 2 (fused final): one 1024-thread block. Thread (q = tid>>8, p = tid&255)
// min-reduces bins p of batches 2q, 2q+1 over the 32 group-partials (coalesced),
// sums all 2048 minima via shuffle+LDS, writes the scalar.
__global__ __launch_bounds__(1024) void chamfer_stage2(
    const float* __restrict__ partial,
    float* __restrict__ out) {
    const int tid = threadIdx.x;
    const int p   = tid & (NP - 1);
    const int q   = tid >> 8;

    float acc = 0.0f;
#pragma unroll
    for (int bq = 0; bq < 2; ++bq) {
        const int b = q * 2 + bq;
        const float* base = partial + (size_t)b * GPB * NP + p;
        float m = 1e30f;
#pragma unroll
        for (int s = 0; s < GPB; ++s)
            m = fminf(m, base[(size_t)s * NP]);
        acc += m;
    }

    for (int off = 32; off > 0; off >>= 1)
        acc += __shfl_down(acc, off, 64);
    __shared__ float wsum[16];
    if ((tid & 63) == 0) wsum[tid >> 6] = acc;
    __syncthreads();
    if (tid == 0) {
        float s = 0.0f;
#pragma unroll
        for (int i = 0; i < 16; ++i) s += wsum[i];
        out[0] = s;
    }
}

extern "C" void kernel_launch(void* const* d_in, const int* in_sizes, int n_in,
                              void* d_out, int out_size, void* d_ws, size_t ws_size,
                              hipStream_t stream) {
    const float* bins    = (const float*)d_in[0];
    const float* targets = (const float*)d_in[1];
    float* out           = (float*)d_out;
    float* partial       = (float*)d_ws;   // [NB][GPB][NP] = 256 KB

    dim3 grid1(GPB, NB);
    chamfer_stage1<<<grid1, 256, 0, stream>>>(bins, targets, partial);
    chamfer_stage2<<<1, 1024, 0, stream>>>(partial, out);
}

// Round 7
// 66.392 us; speedup vs baseline: 1.4351x; 1.0564x over previous
//
#include <hip/hip_runtime.h>

// Problem shape (fixed by setup_inputs): B=8, P=256 bins, M=240*320=76800 pixels.
#define NB   8
#define NP   256
#define MPB  76800
#define WPB  8                    // waves (= target slices) per block
#define PER  300                  // targets per wave; divisible by 4
#define GPB  (MPB / (WPB * PER))  // 32 blocks per batch -> 256 blocks total
#define MIN_DEPTH 0.001f

// Stage 1: block = (group g, batch b), 512 threads = 8 waves (2 waves/SIMD
// for DS-latency hiding). Block stages 2400 targets in LDS (mask applied at
// staging). Each wave scans its own 300-target slice; each LANE owns 4 bins
// (l, l+64, l+128, l+192) so one broadcast ds_read_b128 feeds 16 pair-ops.
// Cross-wave min via LDS, coalesced store of 256 per-block minima. No atomics.
__global__ __launch_bounds__(512) void chamfer_stage1(
    const float* __restrict__ bins,
    const float* __restrict__ targets,
    float* __restrict__ partial) {
    const int b   = blockIdx.y;
    const int g   = blockIdx.x;
    const int tid = threadIdx.x;
    const int w   = tid >> 6;     // wave 0..7
    const int l   = tid & 63;     // lane

    __shared__ float sh[WPB * PER];    // 9.6 KB staged targets
    __shared__ float red[WPB][NP];     // 8 KB cross-wave reduce

    const float4* src = reinterpret_cast<const float4*>(
        targets + (size_t)b * MPB + (size_t)g * (WPB * PER));
    float4* dst = reinterpret_cast<float4*>(sh);
    for (int i = tid; i < WPB * PER / 4; i += 512) {
        float4 t = src[i];
        t.x = (t.x >= MIN_DEPTH) ? t.x : 0.0f;
        t.y = (t.y >= MIN_DEPTH) ? t.y : 0.0f;
        t.z = (t.z >= MIN_DEPTH) ? t.z : 0.0f;
        t.w = (t.w >= MIN_DEPTH) ? t.w : 0.0f;
        dst[i] = t;
    }

    const float* bb = bins + b * (NP + 1);
    const float c0 = 0.5f * (bb[l]       + bb[l + 1]);
    const float c1 = 0.5f * (bb[l + 64]  + bb[l + 65]);
    const float c2 = 0.5f * (bb[l + 128] + bb[l + 129]);
    const float c3 = 0.5f * (bb[l + 192] + bb[l + 193]);

    __syncthreads();

    // 8 independent accumulator chains (2 per bin) for ILP.
    float m00 = 1e30f, m01 = 1e30f, m10 = 1e30f, m11 = 1e30f;
    float m20 = 1e30f, m21 = 1e30f, m30 = 1e30f, m31 = 1e30f;
    const float4* t4 = reinterpret_cast<const float4*>(sh + w * PER);
#pragma unroll 5
    for (int i = 0; i < PER / 4; ++i) {
        float4 t = t4[i];   // broadcast read: all lanes same address
        // fminf(acc, fminf(|a|,|b|)) -> v_min3_f32 with abs modifiers
        m00 = fminf(m00, fminf(fabsf(c0 - t.x), fabsf(c0 - t.y)));
        m01 = fminf(m01, fminf(fabsf(c0 - t.z), fabsf(c0 - t.w)));
        m10 = fminf(m10, fminf(fabsf(c1 - t.x), fabsf(c1 - t.y)));
        m11 = fminf(m11, fminf(fabsf(c1 - t.z), fabsf(c1 - t.w)));
        m20 = fminf(m20, fminf(fabsf(c2 - t.x), fabsf(c2 - t.y)));
        m21 = fminf(m21, fminf(fabsf(c2 - t.z), fabsf(c2 - t.w)));
        m30 = fminf(m30, fminf(fabsf(c3 - t.x), fabsf(c3 - t.y)));
        m31 = fminf(m31, fminf(fabsf(c3 - t.z), fabsf(c3 - t.w)));
    }

    red[w][l]       = fminf(m00, m01);
    red[w][l + 64]  = fminf(m10, m11);
    red[w][l + 128] = fminf(m20, m21);
    red[w][l + 192] = fminf(m30, m31);
    __syncthreads();

    // First 256 threads fold the 8 waves and store coalesced.
    if (tid < NP) {
        float m = 1e30f;
#pragma unroll
        for (int ww = 0; ww < WPB; ++ww)
            m = fminf(m, red[ww][tid]);
        partial[((size_t)b * GPB + g) * NP + tid] = m;
    }
}

// Stage 2 (fused final): one 1024-thread block. Thread (q = tid>>8, p = tid&255)
// min-reduces bin p of batches 2q, 2q+1 over the 32 group-partials (coalesced),
// sums all 2048 minima via shuffle+LDS, writes the scalar.
__global__ __launch_bounds__(1024) void chamfer_stage2(
    const float* __restrict__ partial,
    float* __restrict__ out) {
    const int tid = threadIdx.x;
    const int p   = tid & (NP - 1);
    const int q   = tid >> 8;

    float acc = 0.0f;
#pragma unroll
    for (int bq = 0; bq < 2; ++bq) {
        const int b = q * 2 + bq;
        const float* base = partial + (size_t)b * GPB * NP + p;
        float m = 1e30f;
#pragma unroll
        for (int s = 0; s < GPB; ++s)
            m = fminf(m, base[(size_t)s * NP]);
        acc += m;
    }

    for (int off = 32; off > 0; off >>= 1)
        acc += __shfl_down(acc, off, 64);
    __shared__ float wsum[16];
    if ((tid & 63) == 0) wsum[tid >> 6] = acc;
    __syncthreads();
    if (tid == 0) {
        float s = 0.0f;
#pragma unroll
        for (int i = 0; i < 16; ++i) s += wsum[i];
        out[0] = s;
    }
}

extern "C" void kernel_launch(void* const* d_in, const int* in_sizes, int n_in,
                              void* d_out, int out_size, void* d_ws, size_t ws_size,
                              hipStream_t stream) {
    const float* bins    = (const float*)d_in[0];
    const float* targets = (const float*)d_in[1];
    float* out           = (float*)d_out;
    float* partial       = (float*)d_ws;   // [NB][GPB][NP] = 256 KB

    dim3 grid1(GPB, NB);
    chamfer_stage1<<<grid1, 512, 0, stream>>>(bins, targets, partial);
    chamfer_stage2<<<1, 1024, 0, stream>>>(partial, out);
}

// Round 9
// 65.763 us; speedup vs baseline: 1.4488x; 1.0096x over previous
//
#include <hip/hip_runtime.h>

// Problem shape (fixed by setup_inputs): B=8, P=256 bins, M=240*320=76800 pixels.
#define NB   8
#define NP   256
#define MPB  76800
#define WPB  8                    // waves (= target slices) per block
#define PER  300                  // targets per wave; divisible by 4
#define GPB  (MPB / (WPB * PER))  // 32 blocks per batch -> 256 blocks total
#define MIN_DEPTH 0.001f

// Stage 1: block = (group g, batch b), 512 threads = 8 waves (2 waves/SIMD
// for DS-latency hiding). Block stages 2400 targets in LDS (mask applied at
// staging). Each wave scans its own 300-target slice; each LANE owns 4 bins
// (l, l+64, l+128, l+192) so one broadcast ds_read_b128 feeds 16 pair-ops.
// Cross-wave min via LDS, coalesced store of 256 per-block minima. No atomics.
__global__ __launch_bounds__(512) void chamfer_stage1(
    const float* __restrict__ bins,
    const float* __restrict__ targets,
    float* __restrict__ partial) {
    const int b   = blockIdx.y;
    const int g   = blockIdx.x;
    const int tid = threadIdx.x;
    const int w   = tid >> 6;     // wave 0..7
    const int l   = tid & 63;     // lane

    __shared__ float sh[WPB * PER];    // 9.6 KB staged targets
    __shared__ float red[WPB][NP];     // 8 KB cross-wave reduce

    const float4* src = reinterpret_cast<const float4*>(
        targets + (size_t)b * MPB + (size_t)g * (WPB * PER));
    float4* dst = reinterpret_cast<float4*>(sh);
    for (int i = tid; i < WPB * PER / 4; i += 512) {
        float4 t = src[i];
        t.x = (t.x >= MIN_DEPTH) ? t.x : 0.0f;
        t.y = (t.y >= MIN_DEPTH) ? t.y : 0.0f;
        t.z = (t.z >= MIN_DEPTH) ? t.z : 0.0f;
        t.w = (t.w >= MIN_DEPTH) ? t.w : 0.0f;
        dst[i] = t;
    }

    const float* bb = bins + b * (NP + 1);
    const float c0 = 0.5f * (bb[l]       + bb[l + 1]);
    const float c1 = 0.5f * (bb[l + 64]  + bb[l + 65]);
    const float c2 = 0.5f * (bb[l + 128] + bb[l + 129]);
    const float c3 = 0.5f * (bb[l + 192] + bb[l + 193]);

    __syncthreads();

    // 8 independent accumulator chains (2 per bin) for ILP.
    float m00 = 1e30f, m01 = 1e30f, m10 = 1e30f, m11 = 1e30f;
    float m20 = 1e30f, m21 = 1e30f, m30 = 1e30f, m31 = 1e30f;
    const float4* t4 = reinterpret_cast<const float4*>(sh + w * PER);
#pragma unroll 5
    for (int i = 0; i < PER / 4; ++i) {
        float4 t = t4[i];   // broadcast read: all lanes same address
        // fminf(acc, fminf(|a|,|b|)) -> v_min3_f32 with abs modifiers
        m00 = fminf(m00, fminf(fabsf(c0 - t.x), fabsf(c0 - t.y)));
        m01 = fminf(m01, fminf(fabsf(c0 - t.z), fabsf(c0 - t.w)));
        m10 = fminf(m10, fminf(fabsf(c1 - t.x), fabsf(c1 - t.y)));
        m11 = fminf(m11, fminf(fabsf(c1 - t.z), fabsf(c1 - t.w)));
        m20 = fminf(m20, fminf(fabsf(c2 - t.x), fabsf(c2 - t.y)));
        m21 = fminf(m21, fminf(fabsf(c2 - t.z), fabsf(c2 - t.w)));
        m30 = fminf(m30, fminf(fabsf(c3 - t.x), fabsf(c3 - t.y)));
        m31 = fminf(m31, fminf(fabsf(c3 - t.z), fabsf(c3 - t.w)));
    }

    red[w][l]       = fminf(m00, m01);
    red[w][l + 64]  = fminf(m10, m11);
    red[w][l + 128] = fminf(m20, m21);
    red[w][l + 192] = fminf(m30, m31);
    __syncthreads();

    // First 256 threads fold the 8 waves and store coalesced.
    if (tid < NP) {
        float m = 1e30f;
#pragma unroll
        for (int ww = 0; ww < WPB; ++ww)
            m = fminf(m, red[ww][tid]);
        partial[((size_t)b * GPB + g) * NP + tid] = m;
    }
}

// Stage 2 (fused final): one 512-thread block. Thread t = (b = t>>6, j = t&63)
// owns 4 contiguous bins (4j..4j+3) of batch b: 32 fully-coalesced float4
// loads (stride NP floats along g), per-component min, sum of 4 minima,
// then block sum via shuffle+LDS, write the scalar.
__global__ __launch_bounds__(512) void chamfer_stage2(
    const float* __restrict__ partial,
    float* __restrict__ out) {
    const int tid = threadIdx.x;
    const int b   = tid >> 6;
    const int j   = tid & 63;

    const float4* base = reinterpret_cast<const float4*>(
        partial + (size_t)b * GPB * NP + 4 * j);
    float4 m = {1e30f, 1e30f, 1e30f, 1e30f};
#pragma unroll
    for (int s = 0; s < GPB; ++s) {
        float4 v = base[(size_t)s * (NP / 4)];
        m.x = fminf(m.x, v.x);
        m.y = fminf(m.y, v.y);
        m.z = fminf(m.z, v.z);
        m.w = fminf(m.w, v.w);
    }
    float acc = (m.x + m.y) + (m.z + m.w);

    for (int off = 32; off > 0; off >>= 1)
        acc += __shfl_down(acc, off, 64);
    __shared__ float wsum[8];
    if ((tid & 63) == 0) wsum[tid >> 6] = acc;
    __syncthreads();
    if (tid == 0) {
        float s = 0.0f;
#pragma unroll
        for (int i = 0; i < 8; ++i) s += wsum[i];
        out[0] = s;
    }
}

extern "C" void kernel_launch(void* const* d_in, const int* in_sizes, int n_in,
                              void* d_out, int out_size, void* d_ws, size_t ws_size,
                              hipStream_t stream) {
    const float* bins    = (const float*)d_in[0];
    const float* targets = (const float*)d_in[1];
    float* out           = (float*)d_out;
    float* partial       = (float*)d_ws;   // [NB][GPB][NP] = 256 KB

    dim3 grid1(GPB, NB);
    chamfer_stage1<<<grid1, 512, 0, stream>>>(bins, targets, partial);
    chamfer_stage2<<<1, 512, 0, stream>>>(partial, out);
}